// Round 1
// baseline (1117.855 us; speedup 1.0000x reference)
//
#include <hip/hip_runtime.h>
#include <math.h>

#define N0 32768
#define N1 8192
#define N2 2048
#define E0 262144
#define E1 65536
#define E2 16384
#define EPS 1e-9f

static inline int cdiv(int a, int b){ return (a + b - 1) / b; }

// ---------------- small utility kernels ----------------
__global__ void k_zero_f(float* p, int n){
  int i = blockIdx.x*256 + threadIdx.x;
  if (i < n) p[i] = 0.f;
}
__global__ void k_zero_i(int* p, int n){
  int i = blockIdx.x*256 + threadIdx.x;
  if (i < n) p[i] = 0;
}
__global__ void k_copy_f(const float* __restrict__ a, float* __restrict__ b, int n){
  int i = blockIdx.x*256 + threadIdx.x;
  if (i < n) b[i] = a[i];
}
__global__ void k_gather_pos(const float* __restrict__ pos, const int* __restrict__ idx,
                             float* __restrict__ out, int n){
  int i = blockIdx.x*256 + threadIdx.x;
  if (i < n){
    int s = idx[i];
    out[i*3+0] = pos[s*3+0];
    out[i*3+1] = pos[s*3+1];
    out[i*3+2] = pos[s*3+2];
  }
}
__global__ void k_edge_geo(const float* __restrict__ pos, const int* __restrict__ src,
                           const int* __restrict__ dst, float* __restrict__ rel,
                           float* __restrict__ r, int E){
  int e = blockIdx.x*256 + threadIdx.x;
  if (e < E){
    int s = src[e], d = dst[e];
    float dx = pos[d*3+0]-pos[s*3+0];
    float dy = pos[d*3+1]-pos[s*3+1];
    float dz = pos[d*3+2]-pos[s*3+2];
    rel[e*3+0]=dx; rel[e*3+1]=dy; rel[e*3+2]=dz;
    r[e] = sqrtf(dx*dx+dy*dy+dz*dz+1e-12f);
  }
}

// ---------------- CSR build ----------------
__global__ void k_count(const int* __restrict__ dst, int* cnt, int E){
  int e = blockIdx.x*256 + threadIdx.x;
  if (e < E) atomicAdd(&cnt[dst[e]], 1);
}
// single block, 1024 threads; n <= 32768
__global__ void k_scan(const int* __restrict__ cnt, int* __restrict__ row,
                       int* __restrict__ cur, int n){
  __shared__ int lds[1024];
  int tid = threadIdx.x;
  int chunk = (n + 1023) >> 10;
  int b = tid * chunk;
  int e = b + chunk; if (e > n) e = n;
  int s = 0;
  for (int i = b; i < e; ++i) s += cnt[i];
  lds[tid] = s;
  __syncthreads();
  for (int off = 1; off < 1024; off <<= 1){
    int t = (tid >= off) ? lds[tid - off] : 0;
    __syncthreads();
    lds[tid] += t;
    __syncthreads();
  }
  int base = (tid == 0) ? 0 : lds[tid-1];
  for (int i = b; i < e; ++i){
    row[i] = base; cur[i] = base; base += cnt[i];
  }
  if (tid == 1023) row[n] = lds[1023];
}
__global__ void k_scatter(const int* __restrict__ dst, int* cur, int* __restrict__ eid, int E){
  int e = blockIdx.x*256 + threadIdx.x;
  if (e < E){
    int p = atomicAdd(&cur[dst[e]], 1);
    eid[p] = e;
  }
}

// ---------------- per-layer transforms: q,k,v,skip ----------------
// block = 256 = 8 nodes x 32 lanes (lane = output channel o)
__global__ __launch_bounds__(256) void k_transform(
    const float* __restrict__ x,
    const float* __restrict__ Wq, const float* __restrict__ Wk,
    const float* __restrict__ Wv, const float* __restrict__ Ws,
    float* __restrict__ q, float* __restrict__ k,
    float* __restrict__ v, float* __restrict__ s,
    int n, int Cin, int Cout){
  __shared__ float w4[4][1024];
  __shared__ float xr[8][96];
  int tid = threadIdx.x;
  int nw = Cin * Cout;
  for (int i = tid; i < nw; i += 256){
    w4[0][i] = Wq[i]; w4[1][i] = Wk[i]; w4[2][i] = Wv[i]; w4[3][i] = Ws[i];
  }
  int g = tid >> 5, lane = tid & 31;
  int node = blockIdx.x*8 + g;
  int xl = Cin * 3;
  if (node < n){
    for (int j = lane; j < xl; j += 32) xr[g][j] = x[node*xl + j];
  }
  __syncthreads();
  if (node < n && lane < Cout){
    int OV = Cout*3;
    for (int vv = 0; vv < 3; ++vv){
      float aq=0.f, ak=0.f, av=0.f, as=0.f;
      for (int c = 0; c < Cin; ++c){
        float xv = xr[g][c*3+vv];
        aq += xv * w4[0][c*Cout+lane];
        ak += xv * w4[1][c*Cout+lane];
        av += xv * w4[2][c*Cout+lane];
        as += xv * w4[3][c*Cout+lane];
      }
      int o = node*OV + lane*3 + vv;
      q[o]=aq; k[o]=ak; v[o]=av; s[o]=as;
    }
  }
}

// ---------------- fused attention + skip + GNormBias ----------------
// one 32-lane group per dst node; online softmax over CSR row
__global__ __launch_bounds__(256) void k_attn(
    const float* __restrict__ qb, const float* __restrict__ kb,
    const float* __restrict__ vb, const float* __restrict__ sb,
    const int* __restrict__ row, const int* __restrict__ eid,
    const int* __restrict__ srcA,
    const float* __restrict__ relA, const float* __restrict__ rA,
    const float* __restrict__ wr1, const float* __restrict__ wr2,
    const float* __restrict__ scaleA, const float* __restrict__ biasA,
    float* __restrict__ outb,
    int n, int Cout, float invsc){
  __shared__ float snorm[8][96];
  int tid = threadIdx.x, g = tid >> 5, lane = tid & 31;
  int node = blockIdx.x*8 + g;
  int OV = Cout*3;
  bool act = node < n;
  int jj[3], vc[3];
  #pragma unroll
  for (int kk = 0; kk < 3; ++kk){ jj[kk] = lane + 32*kk; vc[kk] = jj[kk] % 3; }
  float rw1 = (lane < 16) ? wr1[lane] : 0.f;
  float rw2 = (lane < 16) ? wr2[lane] : 0.f;
  if (act){
    int base = node*OV;
    float ql[3];
    #pragma unroll
    for (int kk = 0; kk < 3; ++kk)
      ql[kk] = (jj[kk] < OV) ? qb[base + jj[kk]] * invsc : 0.f;
    float m = -1e30f, z = 0.f;
    float acc[3] = {0.f, 0.f, 0.f};
    int beg = row[node], end = row[node+1];
    for (int i = beg; i < end; ++i){
      int e = eid[i];
      int sn = srcA[e];
      float rr = rA[e];
      int kbase = sn*OV;
      float p = 0.f;
      #pragma unroll
      for (int kk = 0; kk < 3; ++kk)
        if (jj[kk] < OV) p += ql[kk] * kb[kbase + jj[kk]];
      p += fmaxf(rr*rw1, 0.f) * rw2;     // radial MLP terms (lanes 0..15)
      #pragma unroll
      for (int off = 16; off; off >>= 1) p += __shfl_xor(p, off);
      float mn = fmaxf(m, p);
      float cf = __expf(m - mn);
      float w  = __expf(p - mn);
      z = z*cf + w;
      #pragma unroll
      for (int kk = 0; kk < 3; ++kk)
        if (jj[kk] < OV)
          acc[kk] = acc[kk]*cf + w*(vb[kbase + jj[kk]] + relA[e*3 + vc[kk]]);
      m = mn;
    }
    float invz = 1.f / (z + EPS);
    #pragma unroll
    for (int kk = 0; kk < 3; ++kk)
      if (jj[kk] < OV)
        snorm[g][jj[kk]] = acc[kk]*invz + sb[base + jj[kk]];
  }
  __syncthreads();
  if (act && lane < Cout){
    float a = snorm[g][3*lane+0];
    float b = snorm[g][3*lane+1];
    float c = snorm[g][3*lane+2];
    float nrm = sqrtf(a*a + b*b + c*c + 1e-12f);
    float f = fmaxf(scaleA[lane]*nrm + biasA[lane], 0.f) / nrm;
    int base = node*OV + 3*lane;
    outb[base+0] = f*a; outb[base+1] = f*b; outb[base+2] = f*c;
  }
}

// ---------------- pooling / upsample ----------------
__global__ void k_pool_add(const float* __restrict__ x, const int* __restrict__ cl,
                           float* sum, float* cnt, int n0){
  int t = blockIdx.x*256 + threadIdx.x;
  if (t < n0*96){
    int nn = t / 96, j = t - nn*96;
    int c = cl[nn];
    atomicAdd(&sum[c*96 + j], x[t]);
    if (j == 0) atomicAdd(&cnt[c], 1.f);
  }
}
__global__ void k_pool_div(const float* __restrict__ sum, const float* __restrict__ cnt,
                           float* __restrict__ out, int n1){
  int t = blockIdx.x*256 + threadIdx.x;
  if (t < n1*96) out[t] = sum[t] / (cnt[t/96] + EPS);
}
__global__ void k_scatter_add(const float* __restrict__ x, const int* __restrict__ idx,
                              float* out, int n2){
  int t = blockIdx.x*256 + threadIdx.x;
  if (t < n2*96){
    int nn = t / 96, j = t - nn*96;
    out[idx[nn]*96 + j] += x[t];   // idx is a permutation slice -> unique
  }
}

// ---------------- MLP head ----------------
__global__ void k_head(const float* __restrict__ x, const float* __restrict__ W,
                       float* __restrict__ out, int n){
  __shared__ float w[120];
  int tid = threadIdx.x;
  if (tid < 120) w[tid] = W[tid];
  __syncthreads();
  int idx = blockIdx.x*256 + tid;
  if (idx < n*40){
    int nn = idx / 40, o = idx - nn*40;
    float a = x[nn*3+0]*w[o] + x[nn*3+1]*w[40+o] + x[nn*3+2]*w[80+o];
    out[idx] = fmaxf(a, 0.f);
  }
}

extern "C" void kernel_launch(void* const* d_in, const int* in_sizes, int n_in,
                              void* d_out, int out_size, void* d_ws, size_t ws_size,
                              hipStream_t stream){
  // ---- inputs ----
  const float* pos0      = (const float*)d_in[0];
  const float* v0        = (const float*)d_in[1];
  const float* Wq_first  = (const float*)d_in[2];
  const float* Wk_first  = (const float*)d_in[3];
  const float* Wv_first  = (const float*)d_in[4];
  const float* Ws_first  = (const float*)d_in[5];
  const float* Wq_mid    = (const float*)d_in[6];
  const float* Wk_mid    = (const float*)d_in[7];
  const float* Wv_mid    = (const float*)d_in[8];
  const float* Ws_mid    = (const float*)d_in[9];
  const float* Wq_last   = (const float*)d_in[10];
  const float* Wk_last   = (const float*)d_in[11];
  const float* Wv_last   = (const float*)d_in[12];
  const float* Ws_last   = (const float*)d_in[13];
  const float* wr1       = (const float*)d_in[14];
  const float* wr2       = (const float*)d_in[15];
  const float* scale_mid = (const float*)d_in[16];
  const float* bias_mid  = (const float*)d_in[17];
  const float* scale_last= (const float*)d_in[18];
  const float* bias_last = (const float*)d_in[19];
  const float* Wmlp      = (const float*)d_in[20];
  const int* src0 = (const int*)d_in[21];
  const int* dst0 = (const int*)d_in[22];
  const int* src1 = (const int*)d_in[23];
  const int* dst1 = (const int*)d_in[24];
  const int* src2 = (const int*)d_in[25];
  const int* dst2 = (const int*)d_in[26];
  const int* fp1  = (const int*)d_in[27];
  const int* fp2  = (const int*)d_in[28];
  const int* cl1  = (const int*)d_in[29];
  const int* cl2  = (const int*)d_in[30];

  // ---- workspace layout (floats) ----
  float* ws = (float*)d_ws;
  size_t o = 0;
  float* xA  = ws + o; o += (size_t)N0*96;
  float* xB  = ws + o; o += (size_t)N0*96;
  float* x0s = ws + o; o += (size_t)N0*96;
  float* x1s = ws + o; o += (size_t)N1*96;
  float* qb  = ws + o; o += (size_t)N0*96;
  float* kb  = ws + o; o += (size_t)N0*96;
  float* vb  = ws + o; o += (size_t)N0*96;
  float* sb  = ws + o; o += (size_t)N0*96;
  float* pcnt= ws + o; o += N1;
  float* pos1= ws + o; o += (size_t)N1*3;
  float* pos2= ws + o; o += (size_t)N2*3;
  float* rel0= ws + o; o += (size_t)E0*3;
  float* r0  = ws + o; o += E0;
  float* rel1= ws + o; o += (size_t)E1*3;
  float* r1  = ws + o; o += E1;
  float* rel2= ws + o; o += (size_t)E2*3;
  float* r2  = ws + o; o += E2;
  int* ib = (int*)(ws + o);
  size_t io = 0;
  int* row0 = ib + io; io += N0+1;
  int* cnt0 = ib + io; io += N0;
  int* cur0 = ib + io; io += N0;
  int* eid0 = ib + io; io += E0;
  int* row1 = ib + io; io += N1+1;
  int* cnt1 = ib + io; io += N1;
  int* cur1 = ib + io; io += N1;
  int* eid1 = ib + io; io += E1;
  int* row2 = ib + io; io += N2+1;
  int* cnt2 = ib + io; io += N2;
  int* cur2 = ib + io; io += N2;
  int* eid2 = ib + io; io += E2;

  // ---- geometry ----
  k_gather_pos<<<cdiv(N1,256),256,0,stream>>>(pos0, fp1, pos1, N1);
  k_gather_pos<<<cdiv(N2,256),256,0,stream>>>(pos1, fp2, pos2, N2);
  k_edge_geo<<<cdiv(E0,256),256,0,stream>>>(pos0, src0, dst0, rel0, r0, E0);
  k_edge_geo<<<cdiv(E1,256),256,0,stream>>>(pos1, src1, dst1, rel1, r1, E1);
  k_edge_geo<<<cdiv(E2,256),256,0,stream>>>(pos2, src2, dst2, rel2, r2, E2);

  // ---- CSR per level ----
  auto build_csr = [&](const int* dstv, int E, int n, int* cnt, int* row, int* cur, int* eid){
    k_zero_i<<<cdiv(n,256),256,0,stream>>>(cnt, n);
    k_count<<<cdiv(E,256),256,0,stream>>>(dstv, cnt, E);
    k_scan<<<1,1024,0,stream>>>(cnt, row, cur, n);
    k_scatter<<<cdiv(E,256),256,0,stream>>>(dstv, cur, eid, E);
  };
  build_csr(dst0, E0, N0, cnt0, row0, cur0, eid0);
  build_csr(dst1, E1, N1, cnt1, row1, cur1, eid1);
  build_csr(dst2, E2, N2, cnt2, row2, cur2, eid2);

  // ---- layer driver ----
  auto layer = [&](const float* xin, int n, int Cin, int Cout,
                   const float* Wq_, const float* Wk_, const float* Wv_, const float* Ws_,
                   int lidx, const float* scale_, const float* bias_,
                   const int* row, const int* eid, const int* srcv,
                   const float* relv, const float* rv, float* xout){
    k_transform<<<cdiv(n,8),256,0,stream>>>(xin, Wq_, Wk_, Wv_, Ws_, qb, kb, vb, sb, n, Cin, Cout);
    float invsc = 1.f / sqrtf(3.f * (float)Cout);
    k_attn<<<cdiv(n,8),256,0,stream>>>(qb, kb, vb, sb, row, eid, srcv, relv, rv,
                                       wr1 + lidx*16, wr2 + lidx*16, scale_, bias_,
                                       xout, n, Cout, invsc);
  };

  const int C = 32;
  // L0: v0 (Cin=1) -> xA
  layer(v0, N0, 1, C, Wq_first, Wk_first, Wv_first, Ws_first,
        0, scale_mid + 0*C, bias_mid + 0*C, row0, eid0, src0, rel0, r0, xA);
  // L1 -> x0s
  layer(xA, N0, C, C, Wq_mid+0*1024, Wk_mid+0*1024, Wv_mid+0*1024, Ws_mid+0*1024,
        1, scale_mid + 1*C, bias_mid + 1*C, row0, eid0, src0, rel0, r0, x0s);
  // pool1: x0s -> xA(sums) -> xB (level-1 fiber)
  k_zero_f<<<cdiv(N1*96,256),256,0,stream>>>(xA, N1*96);
  k_zero_f<<<cdiv(N1,256),256,0,stream>>>(pcnt, N1);
  k_pool_add<<<cdiv(N0*96,256),256,0,stream>>>(x0s, cl1, xA, pcnt, N0);
  k_pool_div<<<cdiv(N1*96,256),256,0,stream>>>(xA, pcnt, xB, N1);
  // L2 -> xA, L3 -> x1s
  layer(xB, N1, C, C, Wq_mid+1*1024, Wk_mid+1*1024, Wv_mid+1*1024, Ws_mid+1*1024,
        2, scale_mid + 2*C, bias_mid + 2*C, row1, eid1, src1, rel1, r1, xA);
  layer(xA, N1, C, C, Wq_mid+2*1024, Wk_mid+2*1024, Wv_mid+2*1024, Ws_mid+2*1024,
        3, scale_mid + 3*C, bias_mid + 3*C, row1, eid1, src1, rel1, r1, x1s);
  // pool2: x1s -> xA(sums, N2) -> xB (level-2 fiber)
  k_zero_f<<<cdiv(N2*96,256),256,0,stream>>>(xA, N2*96);
  k_zero_f<<<cdiv(N2,256),256,0,stream>>>(pcnt, N2);
  k_pool_add<<<cdiv(N1*96,256),256,0,stream>>>(x1s, cl2, xA, pcnt, N1);
  k_pool_div<<<cdiv(N2*96,256),256,0,stream>>>(xA, pcnt, xB, N2);
  // L4 -> xA, L5 -> xB
  layer(xB, N2, C, C, Wq_mid+3*1024, Wk_mid+3*1024, Wv_mid+3*1024, Ws_mid+3*1024,
        4, scale_mid + 4*C, bias_mid + 4*C, row2, eid2, src2, rel2, r2, xA);
  layer(xA, N2, C, C, Wq_mid+4*1024, Wk_mid+4*1024, Wv_mid+4*1024, Ws_mid+4*1024,
        5, scale_mid + 5*C, bias_mid + 5*C, row2, eid2, src2, rel2, r2, xB);
  // upsample -> level 1: xA = x1s; xA[fp2] += xB
  k_copy_f<<<cdiv(N1*96,256),256,0,stream>>>(x1s, xA, N1*96);
  k_scatter_add<<<cdiv(N2*96,256),256,0,stream>>>(xB, fp2, xA, N2);
  // L6 -> xB, L7 -> xA
  layer(xA, N1, C, C, Wq_mid+5*1024, Wk_mid+5*1024, Wv_mid+5*1024, Ws_mid+5*1024,
        6, scale_mid + 6*C, bias_mid + 6*C, row1, eid1, src1, rel1, r1, xB);
  layer(xB, N1, C, C, Wq_mid+6*1024, Wk_mid+6*1024, Wv_mid+6*1024, Ws_mid+6*1024,
        7, scale_mid + 7*C, bias_mid + 7*C, row1, eid1, src1, rel1, r1, xA);
  // upsample -> level 0: xB = x0s; xB[fp1] += xA
  k_copy_f<<<cdiv(N0*96,256),256,0,stream>>>(x0s, xB, N0*96);
  k_scatter_add<<<cdiv(N1*96,256),256,0,stream>>>(xA, fp1, xB, N1);
  // L8 -> xA
  layer(xB, N0, C, C, Wq_mid+7*1024, Wk_mid+7*1024, Wv_mid+7*1024, Ws_mid+7*1024,
        8, scale_mid + 8*C, bias_mid + 8*C, row0, eid0, src0, rel0, r0, xA);
  // L9 (Cout=1) -> xB (N0*3)
  layer(xA, N0, C, 1, Wq_last, Wk_last, Wv_last, Ws_last,
        9, scale_last, bias_last, row0, eid0, src0, rel0, r0, xB);
  // head
  k_head<<<cdiv(N0*40,256),256,0,stream>>>(xB, Wmlp, (float*)d_out, N0);
}

// Round 2
// 725.726 us; speedup vs baseline: 1.5403x; 1.5403x over previous
//
#include <hip/hip_runtime.h>
#include <math.h>

#define N0 32768
#define N1 8192
#define N2 2048
#define E0 262144
#define E1 65536
#define E2 16384
#define EPS 1e-9f

static inline int cdiv(int a, int b){ return (a + b - 1) / b; }

// ---------------- small utility kernels ----------------
__global__ void k_zero_f(float* p, int n){
  int i = blockIdx.x*256 + threadIdx.x;
  if (i < n) p[i] = 0.f;
}
__global__ void k_zero_i(int* p, int n){
  int i = blockIdx.x*256 + threadIdx.x;
  if (i < n) p[i] = 0;
}
__global__ void k_copy_f(const float* __restrict__ a, float* __restrict__ b, int n){
  int i = blockIdx.x*256 + threadIdx.x;
  if (i < n) b[i] = a[i];
}
__global__ void k_gather_pos(const float* __restrict__ pos, const int* __restrict__ idx,
                             float* __restrict__ out, int n){
  int i = blockIdx.x*256 + threadIdx.x;
  if (i < n){
    int s = idx[i];
    out[i*3+0] = pos[s*3+0];
    out[i*3+1] = pos[s*3+1];
    out[i*3+2] = pos[s*3+2];
  }
}

// ---------------- CSR build (payload permuted inline) ----------------
__global__ void k_count(const int* __restrict__ dst, int* cnt, int E){
  int e = blockIdx.x*256 + threadIdx.x;
  if (e < E) atomicAdd(&cnt[dst[e]], 1);
}
// single block, 1024 threads; n <= 32768
__global__ void k_scan(const int* __restrict__ cnt, int* __restrict__ row,
                       int* __restrict__ cur, int n){
  __shared__ int lds[1024];
  int tid = threadIdx.x;
  int chunk = (n + 1023) >> 10;
  int b = tid * chunk;
  int e = b + chunk; if (e > n) e = n;
  int s = 0;
  for (int i = b; i < e; ++i) s += cnt[i];
  lds[tid] = s;
  __syncthreads();
  for (int off = 1; off < 1024; off <<= 1){
    int t = (tid >= off) ? lds[tid - off] : 0;
    __syncthreads();
    lds[tid] += t;
    __syncthreads();
  }
  int base = (tid == 0) ? 0 : lds[tid-1];
  for (int i = b; i < e; ++i){
    row[i] = base; cur[i] = base; base += cnt[i];
  }
  if (tid == 1023) row[n] = lds[1023];
}
// scatter edge payload (src, r, rel) directly into CSR order; geometry fused
__global__ void k_scatter_geo(const int* __restrict__ src, const int* __restrict__ dst,
                              const float* __restrict__ pos, int* cur,
                              int* __restrict__ srcs, float* __restrict__ rG,
                              float* __restrict__ relG, int E){
  int e = blockIdx.x*256 + threadIdx.x;
  if (e < E){
    int s = src[e], d = dst[e];
    float dx = pos[d*3+0]-pos[s*3+0];
    float dy = pos[d*3+1]-pos[s*3+1];
    float dz = pos[d*3+2]-pos[s*3+2];
    int p = atomicAdd(&cur[d], 1);
    srcs[p] = s;
    rG[p] = sqrtf(dx*dx+dy*dy+dz*dz+1e-12f);
    relG[p*3+0]=dx; relG[p*3+1]=dy; relG[p*3+2]=dz;
  }
}

// ---------------- per-layer transforms: q,k,v,skip ----------------
// block = 256 = 8 nodes x 32 lanes (lane = output channel o)
__global__ __launch_bounds__(256) void k_transform(
    const float* __restrict__ x,
    const float* __restrict__ Wq, const float* __restrict__ Wk,
    const float* __restrict__ Wv, const float* __restrict__ Ws,
    float* __restrict__ q, float* __restrict__ k,
    float* __restrict__ v, float* __restrict__ s,
    int n, int Cin, int Cout){
  __shared__ float w4[4][1024];
  __shared__ float xr[8][96];
  int tid = threadIdx.x;
  int nw = Cin * Cout;
  for (int i = tid; i < nw; i += 256){
    w4[0][i] = Wq[i]; w4[1][i] = Wk[i]; w4[2][i] = Wv[i]; w4[3][i] = Ws[i];
  }
  int g = tid >> 5, lane = tid & 31;
  int node = blockIdx.x*8 + g;
  int xl = Cin * 3;
  if (node < n){
    for (int j = lane; j < xl; j += 32) xr[g][j] = x[node*xl + j];
  }
  __syncthreads();
  if (node < n && lane < Cout){
    int OV = Cout*3;
    for (int vv = 0; vv < 3; ++vv){
      float aq=0.f, ak=0.f, av=0.f, as=0.f;
      for (int c = 0; c < Cin; ++c){
        float xv = xr[g][c*3+vv];
        aq += xv * w4[0][c*Cout+lane];
        ak += xv * w4[1][c*Cout+lane];
        av += xv * w4[2][c*Cout+lane];
        as += xv * w4[3][c*Cout+lane];
      }
      int o = node*OV + lane*3 + vv;
      q[o]=aq; k[o]=ak; v[o]=av; s[o]=as;
    }
  }
}

// ---------------- fused attention + skip + GNormBias ----------------
// one 32-lane group per dst node; chunk-staged metadata + 4-edge batched
// online softmax (group-max rescale) for memory-level parallelism
__global__ __launch_bounds__(256) void k_attn(
    const float* __restrict__ qb, const float* __restrict__ kb,
    const float* __restrict__ vb, const float* __restrict__ sb,
    const int* __restrict__ row, const int* __restrict__ srcs,
    const float* __restrict__ rG, const float* __restrict__ relG,
    const float* __restrict__ wr1, const float* __restrict__ wr2,
    const float* __restrict__ scaleA, const float* __restrict__ biasA,
    float* __restrict__ outb,
    int n, int Cout, float invsc){
  __shared__ float snorm[8][96];
  int tid = threadIdx.x, g = tid >> 5, lane = tid & 31;
  int node = blockIdx.x*8 + g;
  int OV = Cout*3;
  bool act = node < n;
  int jj[3], vc[3];
  #pragma unroll
  for (int kk = 0; kk < 3; ++kk){ jj[kk] = lane + 32*kk; vc[kk] = jj[kk] % 3; }
  float rw1 = (lane < 16) ? wr1[lane] : 0.f;
  float rw2 = (lane < 16) ? wr2[lane] : 0.f;
  if (act){
    int base = node*OV;
    float ql[3];
    #pragma unroll
    for (int kk = 0; kk < 3; ++kk)
      ql[kk] = (jj[kk] < OV) ? qb[base + jj[kk]] * invsc : 0.f;
    float m = -1e30f, z = 0.f;
    float acc[3] = {0.f, 0.f, 0.f};
    int beg = row[node], end = row[node+1];
    for (int cb = beg; cb < end; cb += 32){
      int csz = end - cb; if (csz > 32) csz = 32;
      // stage one edge of metadata per lane (coalesced; CSR-ordered payload)
      int   sn_l = 0;
      float rr_l = 0.f, rx_l = 0.f, ry_l = 0.f, rz_l = 0.f;
      if (lane < csz){
        int idx = cb + lane;
        sn_l = srcs[idx];
        rr_l = rG[idx];
        rx_l = relG[idx*3+0]; ry_l = relG[idx*3+1]; rz_l = relG[idx*3+2];
      }
      for (int j = 0; j < csz; j += 4){
        int gs = csz - j; if (gs > 4) gs = 4;
        int   sid[4]; float rrt[4], rxt[4], ryt[4], rzt[4];
        #pragma unroll
        for (int t = 0; t < 4; ++t){
          int sl = (j + t) & 31;
          sid[t] = __shfl(sn_l, sl, 32);
          rrt[t] = __shfl(rr_l, sl, 32);
          rxt[t] = __shfl(rx_l, sl, 32);
          ryt[t] = __shfl(ry_l, sl, 32);
          rzt[t] = __shfl(rz_l, sl, 32);
        }
        // batched gathers: issue all k & v loads for the group up front
        float kf[4][3], vf[4][3];
        #pragma unroll
        for (int t = 0; t < 4; ++t){
          int kbase = sid[t]*OV;
          #pragma unroll
          for (int kk = 0; kk < 3; ++kk){
            bool ok = (t < gs) && (jj[kk] < OV);
            kf[t][kk] = ok ? kb[kbase + jj[kk]] : 0.f;
            vf[t][kk] = ok ? vb[kbase + jj[kk]] : 0.f;
          }
        }
        // 4 logits (dot + radial bias folded into the same butterfly)
        float p[4];
        #pragma unroll
        for (int t = 0; t < 4; ++t){
          float pt = kf[t][0]*ql[0] + kf[t][1]*ql[1] + kf[t][2]*ql[2];
          pt += fmaxf(rrt[t]*rw1, 0.f) * rw2;   // lanes 0..15 contribute
          #pragma unroll
          for (int off = 16; off; off >>= 1) pt += __shfl_xor(pt, off, 32);
          p[t] = (t < gs) ? pt : -1e30f;
        }
        // single online-softmax rescale per group
        float mn = m;
        #pragma unroll
        for (int t = 0; t < 4; ++t) mn = fmaxf(mn, p[t]);
        float cf = __expf(m - mn);
        z *= cf;
        #pragma unroll
        for (int kk = 0; kk < 3; ++kk) acc[kk] *= cf;
        #pragma unroll
        for (int t = 0; t < 4; ++t){
          float w = __expf(p[t] - mn);          // == 0 for padded slots
          z += w;
          float rc[3] = {rxt[t], ryt[t], rzt[t]};
          #pragma unroll
          for (int kk = 0; kk < 3; ++kk)
            acc[kk] += w * (vf[t][kk] + rc[vc[kk]]);
        }
        m = mn;
      }
    }
    float invz = 1.f / (z + EPS);
    #pragma unroll
    for (int kk = 0; kk < 3; ++kk)
      if (jj[kk] < OV)
        snorm[g][jj[kk]] = acc[kk]*invz + sb[base + jj[kk]];
  }
  __syncthreads();
  if (act && lane < Cout){
    float a = snorm[g][3*lane+0];
    float b = snorm[g][3*lane+1];
    float c = snorm[g][3*lane+2];
    float nrm = sqrtf(a*a + b*b + c*c + 1e-12f);
    float f = fmaxf(scaleA[lane]*nrm + biasA[lane], 0.f) / nrm;
    int base = node*OV + 3*lane;
    outb[base+0] = f*a; outb[base+1] = f*b; outb[base+2] = f*c;
  }
}

// ---------------- pooling / upsample ----------------
__global__ void k_pool_add(const float* __restrict__ x, const int* __restrict__ cl,
                           float* sum, float* cnt, int n0){
  int t = blockIdx.x*256 + threadIdx.x;
  if (t < n0*96){
    int nn = t / 96, j = t - nn*96;
    int c = cl[nn];
    atomicAdd(&sum[c*96 + j], x[t]);
    if (j == 0) atomicAdd(&cnt[c], 1.f);
  }
}
__global__ void k_pool_div(const float* __restrict__ sum, const float* __restrict__ cnt,
                           float* __restrict__ out, int n1){
  int t = blockIdx.x*256 + threadIdx.x;
  if (t < n1*96) out[t] = sum[t] / (cnt[t/96] + EPS);
}
__global__ void k_scatter_add(const float* __restrict__ x, const int* __restrict__ idx,
                              float* out, int n2){
  int t = blockIdx.x*256 + threadIdx.x;
  if (t < n2*96){
    int nn = t / 96, j = t - nn*96;
    out[idx[nn]*96 + j] += x[t];   // idx is a permutation slice -> unique
  }
}

// ---------------- MLP head ----------------
__global__ void k_head(const float* __restrict__ x, const float* __restrict__ W,
                       float* __restrict__ out, int n){
  __shared__ float w[120];
  int tid = threadIdx.x;
  if (tid < 120) w[tid] = W[tid];
  __syncthreads();
  int idx = blockIdx.x*256 + tid;
  if (idx < n*40){
    int nn = idx / 40, o = idx - nn*40;
    float a = x[nn*3+0]*w[o] + x[nn*3+1]*w[40+o] + x[nn*3+2]*w[80+o];
    out[idx] = fmaxf(a, 0.f);
  }
}

extern "C" void kernel_launch(void* const* d_in, const int* in_sizes, int n_in,
                              void* d_out, int out_size, void* d_ws, size_t ws_size,
                              hipStream_t stream){
  // ---- inputs ----
  const float* pos0      = (const float*)d_in[0];
  const float* v0        = (const float*)d_in[1];
  const float* Wq_first  = (const float*)d_in[2];
  const float* Wk_first  = (const float*)d_in[3];
  const float* Wv_first  = (const float*)d_in[4];
  const float* Ws_first  = (const float*)d_in[5];
  const float* Wq_mid    = (const float*)d_in[6];
  const float* Wk_mid    = (const float*)d_in[7];
  const float* Wv_mid    = (const float*)d_in[8];
  const float* Ws_mid    = (const float*)d_in[9];
  const float* Wq_last   = (const float*)d_in[10];
  const float* Wk_last   = (const float*)d_in[11];
  const float* Wv_last   = (const float*)d_in[12];
  const float* Ws_last   = (const float*)d_in[13];
  const float* wr1       = (const float*)d_in[14];
  const float* wr2       = (const float*)d_in[15];
  const float* scale_mid = (const float*)d_in[16];
  const float* bias_mid  = (const float*)d_in[17];
  const float* scale_last= (const float*)d_in[18];
  const float* bias_last = (const float*)d_in[19];
  const float* Wmlp      = (const float*)d_in[20];
  const int* src0 = (const int*)d_in[21];
  const int* dst0 = (const int*)d_in[22];
  const int* src1 = (const int*)d_in[23];
  const int* dst1 = (const int*)d_in[24];
  const int* src2 = (const int*)d_in[25];
  const int* dst2 = (const int*)d_in[26];
  const int* fp1  = (const int*)d_in[27];
  const int* fp2  = (const int*)d_in[28];
  const int* cl1  = (const int*)d_in[29];
  const int* cl2  = (const int*)d_in[30];

  // ---- workspace layout (floats) ----
  float* ws = (float*)d_ws;
  size_t o = 0;
  float* xA  = ws + o; o += (size_t)N0*96;
  float* xB  = ws + o; o += (size_t)N0*96;
  float* x0s = ws + o; o += (size_t)N0*96;
  float* x1s = ws + o; o += (size_t)N1*96;
  float* qb  = ws + o; o += (size_t)N0*96;
  float* kb  = ws + o; o += (size_t)N0*96;
  float* vb  = ws + o; o += (size_t)N0*96;
  float* sb  = ws + o; o += (size_t)N0*96;
  float* pcnt= ws + o; o += N1;
  float* pos1= ws + o; o += (size_t)N1*3;
  float* pos2= ws + o; o += (size_t)N2*3;
  float* relG0= ws + o; o += (size_t)E0*3;
  float* rG0  = ws + o; o += E0;
  float* relG1= ws + o; o += (size_t)E1*3;
  float* rG1  = ws + o; o += E1;
  float* relG2= ws + o; o += (size_t)E2*3;
  float* rG2  = ws + o; o += E2;
  int* ib = (int*)(ws + o);
  size_t io = 0;
  int* row0 = ib + io; io += N0+1;
  int* cnt0 = ib + io; io += N0;
  int* cur0 = ib + io; io += N0;
  int* srcs0= ib + io; io += E0;
  int* row1 = ib + io; io += N1+1;
  int* cnt1 = ib + io; io += N1;
  int* cur1 = ib + io; io += N1;
  int* srcs1= ib + io; io += E1;
  int* row2 = ib + io; io += N2+1;
  int* cnt2 = ib + io; io += N2;
  int* cur2 = ib + io; io += N2;
  int* srcs2= ib + io; io += E2;

  // ---- pooled positions ----
  k_gather_pos<<<cdiv(N1,256),256,0,stream>>>(pos0, fp1, pos1, N1);
  k_gather_pos<<<cdiv(N2,256),256,0,stream>>>(pos1, fp2, pos2, N2);

  // ---- CSR per level (payload permuted, geometry fused) ----
  auto build_csr = [&](const int* srcv, const int* dstv, const float* posv,
                       int E, int n, int* cnt, int* row, int* cur,
                       int* srcsv, float* rGv, float* relGv){
    k_zero_i<<<cdiv(n,256),256,0,stream>>>(cnt, n);
    k_count<<<cdiv(E,256),256,0,stream>>>(dstv, cnt, E);
    k_scan<<<1,1024,0,stream>>>(cnt, row, cur, n);
    k_scatter_geo<<<cdiv(E,256),256,0,stream>>>(srcv, dstv, posv, cur, srcsv, rGv, relGv, E);
  };
  build_csr(src0, dst0, pos0, E0, N0, cnt0, row0, cur0, srcs0, rG0, relG0);
  build_csr(src1, dst1, pos1, E1, N1, cnt1, row1, cur1, srcs1, rG1, relG1);
  build_csr(src2, dst2, pos2, E2, N2, cnt2, row2, cur2, srcs2, rG2, relG2);

  // ---- layer driver ----
  auto layer = [&](const float* xin, int n, int Cin, int Cout,
                   const float* Wq_, const float* Wk_, const float* Wv_, const float* Ws_,
                   int lidx, const float* scale_, const float* bias_,
                   const int* row, const int* srcsv,
                   const float* rGv, const float* relGv, float* xout){
    k_transform<<<cdiv(n,8),256,0,stream>>>(xin, Wq_, Wk_, Wv_, Ws_, qb, kb, vb, sb, n, Cin, Cout);
    float invsc = 1.f / sqrtf(3.f * (float)Cout);
    k_attn<<<cdiv(n,8),256,0,stream>>>(qb, kb, vb, sb, row, srcsv, rGv, relGv,
                                       wr1 + lidx*16, wr2 + lidx*16, scale_, bias_,
                                       xout, n, Cout, invsc);
  };

  const int C = 32;
  // L0: v0 (Cin=1) -> xA
  layer(v0, N0, 1, C, Wq_first, Wk_first, Wv_first, Ws_first,
        0, scale_mid + 0*C, bias_mid + 0*C, row0, srcs0, rG0, relG0, xA);
  // L1 -> x0s
  layer(xA, N0, C, C, Wq_mid+0*1024, Wk_mid+0*1024, Wv_mid+0*1024, Ws_mid+0*1024,
        1, scale_mid + 1*C, bias_mid + 1*C, row0, srcs0, rG0, relG0, x0s);
  // pool1: x0s -> xA(sums) -> xB (level-1 fiber)
  k_zero_f<<<cdiv(N1*96,256),256,0,stream>>>(xA, N1*96);
  k_zero_f<<<cdiv(N1,256),256,0,stream>>>(pcnt, N1);
  k_pool_add<<<cdiv(N0*96,256),256,0,stream>>>(x0s, cl1, xA, pcnt, N0);
  k_pool_div<<<cdiv(N1*96,256),256,0,stream>>>(xA, pcnt, xB, N1);
  // L2 -> xA, L3 -> x1s
  layer(xB, N1, C, C, Wq_mid+1*1024, Wk_mid+1*1024, Wv_mid+1*1024, Ws_mid+1*1024,
        2, scale_mid + 2*C, bias_mid + 2*C, row1, srcs1, rG1, relG1, xA);
  layer(xA, N1, C, C, Wq_mid+2*1024, Wk_mid+2*1024, Wv_mid+2*1024, Ws_mid+2*1024,
        3, scale_mid + 3*C, bias_mid + 3*C, row1, srcs1, rG1, relG1, x1s);
  // pool2: x1s -> xA(sums, N2) -> xB (level-2 fiber)
  k_zero_f<<<cdiv(N2*96,256),256,0,stream>>>(xA, N2*96);
  k_zero_f<<<cdiv(N2,256),256,0,stream>>>(pcnt, N2);
  k_pool_add<<<cdiv(N1*96,256),256,0,stream>>>(x1s, cl2, xA, pcnt, N1);
  k_pool_div<<<cdiv(N2*96,256),256,0,stream>>>(xA, pcnt, xB, N2);
  // L4 -> xA, L5 -> xB
  layer(xB, N2, C, C, Wq_mid+3*1024, Wk_mid+3*1024, Wv_mid+3*1024, Ws_mid+3*1024,
        4, scale_mid + 4*C, bias_mid + 4*C, row2, srcs2, rG2, relG2, xA);
  layer(xA, N2, C, C, Wq_mid+4*1024, Wk_mid+4*1024, Wv_mid+4*1024, Ws_mid+4*1024,
        5, scale_mid + 5*C, bias_mid + 5*C, row2, srcs2, rG2, relG2, xB);
  // upsample -> level 1: xA = x1s; xA[fp2] += xB
  k_copy_f<<<cdiv(N1*96,256),256,0,stream>>>(x1s, xA, N1*96);
  k_scatter_add<<<cdiv(N2*96,256),256,0,stream>>>(xB, fp2, xA, N2);
  // L6 -> xB, L7 -> xA
  layer(xA, N1, C, C, Wq_mid+5*1024, Wk_mid+5*1024, Wv_mid+5*1024, Ws_mid+5*1024,
        6, scale_mid + 6*C, bias_mid + 6*C, row1, srcs1, rG1, relG1, xB);
  layer(xB, N1, C, C, Wq_mid+6*1024, Wk_mid+6*1024, Wv_mid+6*1024, Ws_mid+6*1024,
        7, scale_mid + 7*C, bias_mid + 7*C, row1, srcs1, rG1, relG1, xA);
  // upsample -> level 0: xB = x0s; xB[fp1] += xA
  k_copy_f<<<cdiv(N0*96,256),256,0,stream>>>(x0s, xB, N0*96);
  k_scatter_add<<<cdiv(N1*96,256),256,0,stream>>>(xA, fp1, xB, N1);
  // L8 -> xA
  layer(xB, N0, C, C, Wq_mid+7*1024, Wk_mid+7*1024, Wv_mid+7*1024, Ws_mid+7*1024,
        8, scale_mid + 8*C, bias_mid + 8*C, row0, srcs0, rG0, relG0, xA);
  // L9 (Cout=1) -> xB (N0*3)
  layer(xA, N0, C, 1, Wq_last, Wk_last, Wv_last, Ws_last,
        9, scale_last, bias_last, row0, srcs0, rG0, relG0, xB);
  // head
  k_head<<<cdiv(N0*40,256),256,0,stream>>>(xB, Wmlp, (float*)d_out, N0);
}

// Round 3
// 652.669 us; speedup vs baseline: 1.7127x; 1.1119x over previous
//
#include <hip/hip_runtime.h>
#include <math.h>

#define N0 32768
#define N1 8192
#define N2 2048
#define E0 262144
#define E1 65536
#define E2 16384
#define EPS 1e-9f

static inline int cdiv(int a, int b){ return (a + b - 1) / b; }

// ---------------- small utility kernels ----------------
__global__ void k_zero_f(float* p, int n){
  int i = blockIdx.x*256 + threadIdx.x;
  if (i < n) p[i] = 0.f;
}
__global__ void k_zero_i(int* p, int n){
  int i = blockIdx.x*256 + threadIdx.x;
  if (i < n) p[i] = 0;
}
__global__ void k_copy_f(const float* __restrict__ a, float* __restrict__ b, int n){
  int i = blockIdx.x*256 + threadIdx.x;
  if (i < n) b[i] = a[i];
}
__global__ void k_gather_pos(const float* __restrict__ pos, const int* __restrict__ idx,
                             float* __restrict__ out, int n){
  int i = blockIdx.x*256 + threadIdx.x;
  if (i < n){
    int s = idx[i];
    out[i*3+0] = pos[s*3+0];
    out[i*3+1] = pos[s*3+1];
    out[i*3+2] = pos[s*3+2];
  }
}

// ---------------- CSR build (payload permuted inline) ----------------
__global__ void k_count(const int* __restrict__ dst, int* cnt, int E){
  int e = blockIdx.x*256 + threadIdx.x;
  if (e < E) atomicAdd(&cnt[dst[e]], 1);
}
// hierarchical exclusive scan: pass 1 — per-block scan + block sums
__global__ __launch_bounds__(256) void k_scan1(const int* __restrict__ cnt,
                                               int* __restrict__ excl,
                                               int* __restrict__ bsum, int n){
  __shared__ int lds[256];
  int tid = threadIdx.x;
  int i = blockIdx.x*256 + tid;
  int v = (i < n) ? cnt[i] : 0;
  lds[tid] = v;
  __syncthreads();
  for (int off = 1; off < 256; off <<= 1){
    int t = (tid >= off) ? lds[tid - off] : 0;
    __syncthreads();
    lds[tid] += t;
    __syncthreads();
  }
  if (i < n) excl[i] = lds[tid] - v;
  if (tid == 255) bsum[blockIdx.x] = lds[255];
}
// pass 2 — single block exclusive-scans block sums (nb <= 256)
__global__ __launch_bounds__(256) void k_scan2(int* bsum, int nb){
  __shared__ int lds[256];
  int tid = threadIdx.x;
  int v = (tid < nb) ? bsum[tid] : 0;
  lds[tid] = v;
  __syncthreads();
  for (int off = 1; off < 256; off <<= 1){
    int t = (tid >= off) ? lds[tid - off] : 0;
    __syncthreads();
    lds[tid] += t;
    __syncthreads();
  }
  if (tid < nb) bsum[tid] = lds[tid] - v;
}
// pass 3 — add block offsets, emit row & cur, row[n]=E
__global__ __launch_bounds__(256) void k_scan3(const int* __restrict__ excl,
                                               const int* __restrict__ bsum,
                                               int* __restrict__ row,
                                               int* __restrict__ cur, int n, int E){
  int i = blockIdx.x*256 + threadIdx.x;
  if (i < n){
    int r = excl[i] + bsum[blockIdx.x];
    row[i] = r; cur[i] = r;
  }
  if (i == 0) row[n] = E;
}
// scatter edge payload (src, r, rel) directly into CSR order; geometry fused
__global__ void k_scatter_geo(const int* __restrict__ src, const int* __restrict__ dst,
                              const float* __restrict__ pos, int* cur,
                              int* __restrict__ srcs, float* __restrict__ rG,
                              float* __restrict__ relG, int E){
  int e = blockIdx.x*256 + threadIdx.x;
  if (e < E){
    int s = src[e], d = dst[e];
    float dx = pos[d*3+0]-pos[s*3+0];
    float dy = pos[d*3+1]-pos[s*3+1];
    float dz = pos[d*3+2]-pos[s*3+2];
    int p = atomicAdd(&cur[d], 1);
    srcs[p] = s;
    rG[p] = sqrtf(dx*dx+dy*dy+dz*dz+1e-12f);
    relG[p*3+0]=dx; relG[p*3+1]=dy; relG[p*3+2]=dz;
  }
}

// ---------------- per-layer transforms: q,k,v,skip ----------------
// block = 256 = 8 nodes x 32 lanes (lane = output channel o)
__global__ __launch_bounds__(256) void k_transform(
    const float* __restrict__ x,
    const float* __restrict__ Wq, const float* __restrict__ Wk,
    const float* __restrict__ Wv, const float* __restrict__ Ws,
    float* __restrict__ q, float* __restrict__ k,
    float* __restrict__ v, float* __restrict__ s,
    int n, int Cin, int Cout){
  __shared__ float w4[4][1024];
  __shared__ float xr[8][96];
  int tid = threadIdx.x;
  int nw = Cin * Cout;
  for (int i = tid; i < nw; i += 256){
    w4[0][i] = Wq[i]; w4[1][i] = Wk[i]; w4[2][i] = Wv[i]; w4[3][i] = Ws[i];
  }
  int g = tid >> 5, lane = tid & 31;
  int node = blockIdx.x*8 + g;
  int xl = Cin * 3;
  if (node < n){
    for (int j = lane; j < xl; j += 32) xr[g][j] = x[node*xl + j];
  }
  __syncthreads();
  if (node < n && lane < Cout){
    int OV = Cout*3;
    for (int vv = 0; vv < 3; ++vv){
      float aq=0.f, ak=0.f, av=0.f, as=0.f;
      for (int c = 0; c < Cin; ++c){
        float xv = xr[g][c*3+vv];
        aq += xv * w4[0][c*Cout+lane];
        ak += xv * w4[1][c*Cout+lane];
        av += xv * w4[2][c*Cout+lane];
        as += xv * w4[3][c*Cout+lane];
      }
      int o = node*OV + lane*3 + vv;
      q[o]=aq; k[o]=ak; v[o]=av; s[o]=as;
    }
  }
}

// ---------------- fused attention + skip + GNormBias ----------------
// one 32-lane group per dst node; chunk-staged metadata + 4-edge batched
// online softmax (group-max rescale) for memory-level parallelism
__global__ __launch_bounds__(256) void k_attn(
    const float* __restrict__ qb, const float* __restrict__ kb,
    const float* __restrict__ vb, const float* __restrict__ sb,
    const int* __restrict__ row, const int* __restrict__ srcs,
    const float* __restrict__ rG, const float* __restrict__ relG,
    const float* __restrict__ wr1, const float* __restrict__ wr2,
    const float* __restrict__ scaleA, const float* __restrict__ biasA,
    float* __restrict__ outb,
    int n, int Cout, float invsc){
  __shared__ float snorm[8][96];
  int tid = threadIdx.x, g = tid >> 5, lane = tid & 31;
  int node = blockIdx.x*8 + g;
  int OV = Cout*3;
  bool act = node < n;
  int jj[3], vc[3];
  #pragma unroll
  for (int kk = 0; kk < 3; ++kk){ jj[kk] = lane + 32*kk; vc[kk] = jj[kk] % 3; }
  float rw1 = (lane < 16) ? wr1[lane] : 0.f;
  float rw2 = (lane < 16) ? wr2[lane] : 0.f;
  if (act){
    int base = node*OV;
    float ql[3];
    #pragma unroll
    for (int kk = 0; kk < 3; ++kk)
      ql[kk] = (jj[kk] < OV) ? qb[base + jj[kk]] * invsc : 0.f;
    float m = -1e30f, z = 0.f;
    float acc[3] = {0.f, 0.f, 0.f};
    int beg = row[node], end = row[node+1];
    for (int cb = beg; cb < end; cb += 32){
      int csz = end - cb; if (csz > 32) csz = 32;
      // stage one edge of metadata per lane (coalesced; CSR-ordered payload)
      int   sn_l = 0;
      float rr_l = 0.f, rx_l = 0.f, ry_l = 0.f, rz_l = 0.f;
      if (lane < csz){
        int idx = cb + lane;
        sn_l = srcs[idx];
        rr_l = rG[idx];
        rx_l = relG[idx*3+0]; ry_l = relG[idx*3+1]; rz_l = relG[idx*3+2];
      }
      for (int j = 0; j < csz; j += 4){
        int gs = csz - j; if (gs > 4) gs = 4;
        int   sid[4]; float rrt[4], rxt[4], ryt[4], rzt[4];
        #pragma unroll
        for (int t = 0; t < 4; ++t){
          int sl = (j + t) & 31;
          sid[t] = __shfl(sn_l, sl, 32);
          rrt[t] = __shfl(rr_l, sl, 32);
          rxt[t] = __shfl(rx_l, sl, 32);
          ryt[t] = __shfl(ry_l, sl, 32);
          rzt[t] = __shfl(rz_l, sl, 32);
        }
        // batched gathers: issue all k & v loads for the group up front
        float kf[4][3], vf[4][3];
        #pragma unroll
        for (int t = 0; t < 4; ++t){
          int kbase = sid[t]*OV;
          #pragma unroll
          for (int kk = 0; kk < 3; ++kk){
            bool ok = (t < gs) && (jj[kk] < OV);
            kf[t][kk] = ok ? kb[kbase + jj[kk]] : 0.f;
            vf[t][kk] = ok ? vb[kbase + jj[kk]] : 0.f;
          }
        }
        // 4 logits (dot + radial bias folded into the same butterfly)
        float p[4];
        #pragma unroll
        for (int t = 0; t < 4; ++t){
          float pt = kf[t][0]*ql[0] + kf[t][1]*ql[1] + kf[t][2]*ql[2];
          pt += fmaxf(rrt[t]*rw1, 0.f) * rw2;   // lanes 0..15 contribute
          #pragma unroll
          for (int off = 16; off; off >>= 1) pt += __shfl_xor(pt, off, 32);
          p[t] = (t < gs) ? pt : -1e30f;
        }
        // single online-softmax rescale per group
        float mn = m;
        #pragma unroll
        for (int t = 0; t < 4; ++t) mn = fmaxf(mn, p[t]);
        float cf = __expf(m - mn);
        z *= cf;
        #pragma unroll
        for (int kk = 0; kk < 3; ++kk) acc[kk] *= cf;
        #pragma unroll
        for (int t = 0; t < 4; ++t){
          float w = __expf(p[t] - mn);          // == 0 for padded slots
          z += w;
          float rc[3] = {rxt[t], ryt[t], rzt[t]};
          #pragma unroll
          for (int kk = 0; kk < 3; ++kk)
            acc[kk] += w * (vf[t][kk] + rc[vc[kk]]);
        }
        m = mn;
      }
    }
    float invz = 1.f / (z + EPS);
    #pragma unroll
    for (int kk = 0; kk < 3; ++kk)
      if (jj[kk] < OV)
        snorm[g][jj[kk]] = acc[kk]*invz + sb[base + jj[kk]];
  }
  __syncthreads();
  if (act && lane < Cout){
    float a = snorm[g][3*lane+0];
    float b = snorm[g][3*lane+1];
    float c = snorm[g][3*lane+2];
    float nrm = sqrtf(a*a + b*b + c*c + 1e-12f);
    float f = fmaxf(scaleA[lane]*nrm + biasA[lane], 0.f) / nrm;
    int base = node*OV + 3*lane;
    outb[base+0] = f*a; outb[base+1] = f*b; outb[base+2] = f*c;
  }
}

// ---------------- pooling / upsample ----------------
__global__ void k_pool_add(const float* __restrict__ x, const int* __restrict__ cl,
                           float* sum, float* cnt, int n0){
  int t = blockIdx.x*256 + threadIdx.x;
  if (t < n0*96){
    int nn = t / 96, j = t - nn*96;
    int c = cl[nn];
    atomicAdd(&sum[c*96 + j], x[t]);
    if (j == 0) atomicAdd(&cnt[c], 1.f);
  }
}
__global__ void k_pool_div(const float* __restrict__ sum, const float* __restrict__ cnt,
                           float* __restrict__ out, int n1){
  int t = blockIdx.x*256 + threadIdx.x;
  if (t < n1*96) out[t] = sum[t] / (cnt[t/96] + EPS);
}
__global__ void k_scatter_add(const float* __restrict__ x, const int* __restrict__ idx,
                              float* out, int n2){
  int t = blockIdx.x*256 + threadIdx.x;
  if (t < n2*96){
    int nn = t / 96, j = t - nn*96;
    out[idx[nn]*96 + j] += x[t];   // idx is a permutation slice -> unique
  }
}

// ---------------- MLP head ----------------
__global__ void k_head(const float* __restrict__ x, const float* __restrict__ W,
                       float* __restrict__ out, int n){
  __shared__ float w[120];
  int tid = threadIdx.x;
  if (tid < 120) w[tid] = W[tid];
  __syncthreads();
  int idx = blockIdx.x*256 + tid;
  if (idx < n*40){
    int nn = idx / 40, o = idx - nn*40;
    float a = x[nn*3+0]*w[o] + x[nn*3+1]*w[40+o] + x[nn*3+2]*w[80+o];
    out[idx] = fmaxf(a, 0.f);
  }
}

extern "C" void kernel_launch(void* const* d_in, const int* in_sizes, int n_in,
                              void* d_out, int out_size, void* d_ws, size_t ws_size,
                              hipStream_t stream){
  // ---- inputs ----
  const float* pos0      = (const float*)d_in[0];
  const float* v0        = (const float*)d_in[1];
  const float* Wq_first  = (const float*)d_in[2];
  const float* Wk_first  = (const float*)d_in[3];
  const float* Wv_first  = (const float*)d_in[4];
  const float* Ws_first  = (const float*)d_in[5];
  const float* Wq_mid    = (const float*)d_in[6];
  const float* Wk_mid    = (const float*)d_in[7];
  const float* Wv_mid    = (const float*)d_in[8];
  const float* Ws_mid    = (const float*)d_in[9];
  const float* Wq_last   = (const float*)d_in[10];
  const float* Wk_last   = (const float*)d_in[11];
  const float* Wv_last   = (const float*)d_in[12];
  const float* Ws_last   = (const float*)d_in[13];
  const float* wr1       = (const float*)d_in[14];
  const float* wr2       = (const float*)d_in[15];
  const float* scale_mid = (const float*)d_in[16];
  const float* bias_mid  = (const float*)d_in[17];
  const float* scale_last= (const float*)d_in[18];
  const float* bias_last = (const float*)d_in[19];
  const float* Wmlp      = (const float*)d_in[20];
  const int* src0 = (const int*)d_in[21];
  const int* dst0 = (const int*)d_in[22];
  const int* src1 = (const int*)d_in[23];
  const int* dst1 = (const int*)d_in[24];
  const int* src2 = (const int*)d_in[25];
  const int* dst2 = (const int*)d_in[26];
  const int* fp1  = (const int*)d_in[27];
  const int* fp2  = (const int*)d_in[28];
  const int* cl1  = (const int*)d_in[29];
  const int* cl2  = (const int*)d_in[30];

  // ---- workspace layout (floats) ----
  float* ws = (float*)d_ws;
  size_t o = 0;
  float* xA  = ws + o; o += (size_t)N0*96;
  float* xB  = ws + o; o += (size_t)N0*96;
  float* x0s = ws + o; o += (size_t)N0*96;
  float* x1s = ws + o; o += (size_t)N1*96;
  float* qb  = ws + o; o += (size_t)N0*96;
  float* kb  = ws + o; o += (size_t)N0*96;
  float* vb  = ws + o; o += (size_t)N0*96;
  float* sb  = ws + o; o += (size_t)N0*96;
  float* pcnt= ws + o; o += N1;
  float* pos1= ws + o; o += (size_t)N1*3;
  float* pos2= ws + o; o += (size_t)N2*3;
  float* relG0= ws + o; o += (size_t)E0*3;
  float* rG0  = ws + o; o += E0;
  float* relG1= ws + o; o += (size_t)E1*3;
  float* rG1  = ws + o; o += E1;
  float* relG2= ws + o; o += (size_t)E2*3;
  float* rG2  = ws + o; o += E2;
  int* ib = (int*)(ws + o);
  size_t io = 0;
  int* row0 = ib + io; io += N0+1;
  int* cnt0 = ib + io; io += N0;
  int* cur0 = ib + io; io += N0;
  int* srcs0= ib + io; io += E0;
  int* row1 = ib + io; io += N1+1;
  int* cnt1 = ib + io; io += N1;
  int* cur1 = ib + io; io += N1;
  int* srcs1= ib + io; io += E1;
  int* row2 = ib + io; io += N2+1;
  int* cnt2 = ib + io; io += N2;
  int* cur2 = ib + io; io += N2;
  int* srcs2= ib + io; io += E2;
  int* excl = ib + io; io += N0;      // scan scratch (max level size)
  int* bsum = ib + io; io += 256;     // block sums (<=128 blocks)

  // ---- pooled positions ----
  k_gather_pos<<<cdiv(N1,256),256,0,stream>>>(pos0, fp1, pos1, N1);
  k_gather_pos<<<cdiv(N2,256),256,0,stream>>>(pos1, fp2, pos2, N2);

  // ---- CSR per level (payload permuted, geometry fused, parallel scan) ----
  auto build_csr = [&](const int* srcv, const int* dstv, const float* posv,
                       int E, int n, int* cnt, int* row, int* cur,
                       int* srcsv, float* rGv, float* relGv){
    int nb = cdiv(n, 256);
    k_zero_i<<<cdiv(n,256),256,0,stream>>>(cnt, n);
    k_count<<<cdiv(E,256),256,0,stream>>>(dstv, cnt, E);
    k_scan1<<<nb,256,0,stream>>>(cnt, excl, bsum, n);
    k_scan2<<<1,256,0,stream>>>(bsum, nb);
    k_scan3<<<nb,256,0,stream>>>(excl, bsum, row, cur, n, E);
    k_scatter_geo<<<cdiv(E,256),256,0,stream>>>(srcv, dstv, posv, cur, srcsv, rGv, relGv, E);
  };
  build_csr(src0, dst0, pos0, E0, N0, cnt0, row0, cur0, srcs0, rG0, relG0);
  build_csr(src1, dst1, pos1, E1, N1, cnt1, row1, cur1, srcs1, rG1, relG1);
  build_csr(src2, dst2, pos2, E2, N2, cnt2, row2, cur2, srcs2, rG2, relG2);

  // ---- layer driver ----
  auto layer = [&](const float* xin, int n, int Cin, int Cout,
                   const float* Wq_, const float* Wk_, const float* Wv_, const float* Ws_,
                   int lidx, const float* scale_, const float* bias_,
                   const int* row, const int* srcsv,
                   const float* rGv, const float* relGv, float* xout){
    k_transform<<<cdiv(n,8),256,0,stream>>>(xin, Wq_, Wk_, Wv_, Ws_, qb, kb, vb, sb, n, Cin, Cout);
    float invsc = 1.f / sqrtf(3.f * (float)Cout);
    k_attn<<<cdiv(n,8),256,0,stream>>>(qb, kb, vb, sb, row, srcsv, rGv, relGv,
                                       wr1 + lidx*16, wr2 + lidx*16, scale_, bias_,
                                       xout, n, Cout, invsc);
  };

  const int C = 32;
  // L0: v0 (Cin=1) -> xA
  layer(v0, N0, 1, C, Wq_first, Wk_first, Wv_first, Ws_first,
        0, scale_mid + 0*C, bias_mid + 0*C, row0, srcs0, rG0, relG0, xA);
  // L1 -> x0s
  layer(xA, N0, C, C, Wq_mid+0*1024, Wk_mid+0*1024, Wv_mid+0*1024, Ws_mid+0*1024,
        1, scale_mid + 1*C, bias_mid + 1*C, row0, srcs0, rG0, relG0, x0s);
  // pool1: x0s -> xA(sums) -> xB (level-1 fiber)
  k_zero_f<<<cdiv(N1*96,256),256,0,stream>>>(xA, N1*96);
  k_zero_f<<<cdiv(N1,256),256,0,stream>>>(pcnt, N1);
  k_pool_add<<<cdiv(N0*96,256),256,0,stream>>>(x0s, cl1, xA, pcnt, N0);
  k_pool_div<<<cdiv(N1*96,256),256,0,stream>>>(xA, pcnt, xB, N1);
  // L2 -> xA, L3 -> x1s
  layer(xB, N1, C, C, Wq_mid+1*1024, Wk_mid+1*1024, Wv_mid+1*1024, Ws_mid+1*1024,
        2, scale_mid + 2*C, bias_mid + 2*C, row1, srcs1, rG1, relG1, xA);
  layer(xA, N1, C, C, Wq_mid+2*1024, Wk_mid+2*1024, Wv_mid+2*1024, Ws_mid+2*1024,
        3, scale_mid + 3*C, bias_mid + 3*C, row1, srcs1, rG1, relG1, x1s);
  // pool2: x1s -> xA(sums, N2) -> xB (level-2 fiber)
  k_zero_f<<<cdiv(N2*96,256),256,0,stream>>>(xA, N2*96);
  k_zero_f<<<cdiv(N2,256),256,0,stream>>>(pcnt, N2);
  k_pool_add<<<cdiv(N1*96,256),256,0,stream>>>(x1s, cl2, xA, pcnt, N1);
  k_pool_div<<<cdiv(N2*96,256),256,0,stream>>>(xA, pcnt, xB, N2);
  // L4 -> xA, L5 -> xB
  layer(xB, N2, C, C, Wq_mid+3*1024, Wk_mid+3*1024, Wv_mid+3*1024, Ws_mid+3*1024,
        4, scale_mid + 4*C, bias_mid + 4*C, row2, srcs2, rG2, relG2, xA);
  layer(xA, N2, C, C, Wq_mid+4*1024, Wk_mid+4*1024, Wv_mid+4*1024, Ws_mid+4*1024,
        5, scale_mid + 5*C, bias_mid + 5*C, row2, srcs2, rG2, relG2, xB);
  // upsample -> level 1: xA = x1s; xA[fp2] += xB
  k_copy_f<<<cdiv(N1*96,256),256,0,stream>>>(x1s, xA, N1*96);
  k_scatter_add<<<cdiv(N2*96,256),256,0,stream>>>(xB, fp2, xA, N2);
  // L6 -> xB, L7 -> xA
  layer(xA, N1, C, C, Wq_mid+5*1024, Wk_mid+5*1024, Wv_mid+5*1024, Ws_mid+5*1024,
        6, scale_mid + 6*C, bias_mid + 6*C, row1, srcs1, rG1, relG1, xB);
  layer(xB, N1, C, C, Wq_mid+6*1024, Wk_mid+6*1024, Wv_mid+6*1024, Ws_mid+6*1024,
        7, scale_mid + 7*C, bias_mid + 7*C, row1, srcs1, rG1, relG1, xA);
  // upsample -> level 0: xB = x0s; xB[fp1] += xA
  k_copy_f<<<cdiv(N0*96,256),256,0,stream>>>(x0s, xB, N0*96);
  k_scatter_add<<<cdiv(N1*96,256),256,0,stream>>>(xA, fp1, xB, N1);
  // L8 -> xA
  layer(xB, N0, C, C, Wq_mid+7*1024, Wk_mid+7*1024, Wv_mid+7*1024, Ws_mid+7*1024,
        8, scale_mid + 8*C, bias_mid + 8*C, row0, srcs0, rG0, relG0, xA);
  // L9 (Cout=1) -> xB (N0*3)
  layer(xA, N0, C, 1, Wq_last, Wk_last, Wv_last, Ws_last,
        9, scale_last, bias_last, row0, srcs0, rG0, relG0, xB);
  // head
  k_head<<<cdiv(N0*40,256),256,0,stream>>>(xB, Wmlp, (float*)d_out, N0);
}